// Round 1
// baseline (169.895 us; speedup 1.0000x reference)
//
#include <hip/hip_runtime.h>
#include <math.h>

#define NSs 6
#define NTs 4
#define Bb  2
#define Nn  32
#define Hh  768
#define Ww  768
#define Rr  28
#define Cch 10
#define NCH 38
#define HW  (Hh*Ww)
#define NEGD (-100.0)

struct InstP {
  int y0, x0, y1r, x1r;   // inst box [y0,y1r) x [x0,x1r)
  int ys, ye, xs, xe;     // mask box
  float sc_y, sc_x;       // 28.f/h, 28.f/w  (f32 to match ref's R/h)
  int tc;                 // NS + cls  (thing channel)
  int mskoff;             // element offset of selected 28x28 mask
};

__device__ __forceinline__ double sigd(double x) { return 1.0 / (1.0 + exp(-x)); }

__global__ void k_zero(int* __restrict__ p, int n) {
  for (int i = threadIdx.x; i < n; i += 256) p[i] = 0;
}

__global__ __launch_bounds__(256) void k_fuse(
    const float* __restrict__ sem, const float* __restrict__ roi,
    const float* __restrict__ bbx, const int* __restrict__ cls,
    int* __restrict__ out_pred, int* __restrict__ g_hist, int* __restrict__ g_scount)
{
  __shared__ InstP spar[Nn];
  __shared__ int s_hist[Nn*Cch];
  __shared__ int s_sc[NSs];
  __shared__ unsigned s_rel;

  const int bid  = blockIdx.x;
  const int xseg = bid % (Ww/256);
  const int y    = (bid / (Ww/256)) % Hh;
  const int b    = bid / ((Ww/256)*Hh);
  const int x0b  = xseg * 256;
  const int tid  = threadIdx.x;

  if (tid == 0) s_rel = 0u;
  for (int i = tid; i < Nn*Cch; i += 256) s_hist[i] = 0;
  if (tid < NSs) s_sc[tid] = 0;
  if (tid < Nn) {
    const int n = tid;
    const float* bbp = bbx + ((size_t)b*Nn + n)*4;
    float f0 = bbp[0], f1 = bbp[1], f2 = bbp[2], f3 = bbp[3];
    int y0 = (int)floorf(f0), x0 = (int)floorf(f1);
    int y1 = (int)floorf(f2), x1 = (int)floorf(f3);
    int y1r = (int)(rintf(f2) + 1.0f);   // jnp.round = half-to-even
    int x1r = (int)(rintf(f3) + 1.0f);
    float hh = fmaxf((float)(y1 - y0 + 1), 1.0f);
    float wd = fmaxf((float)(x1 - x0 + 1), 1.0f);
    InstP p;
    p.y0 = y0; p.x0 = x0; p.y1r = y1r; p.x1r = x1r;
    p.ys = max(y0, 0); p.ye = min(y1 + 1, Hh);
    p.xs = max(x0, 0); p.xe = min(x1 + 1, Ww);
    p.sc_y = 28.0f / hh; p.sc_x = 28.0f / wd;
    int cl = cls[b*Nn + n];
    p.tc = NSs + cl;
    p.mskoff = (((b*Nn + n)*NTs) + cl)*Rr*Rr;
    spar[n] = p;
    bool rel_i = (y >= y0)   && (y < y1r)  && (x0   <= x0b + 255) && (x1r  > x0b);
    bool rel_m = (y >= p.ys) && (y < p.ye) && (p.xs <= x0b + 255) && (p.xe > x0b);
    if (rel_i || rel_m) atomicOr(&s_rel, 1u << n);
  }
  __syncthreads();

  const int x = x0b + tid;
  const float* cp = sem + (size_t)b*Cch*HW + (size_t)y*Ww + x;
  float ch[Cch];
#pragma unroll
  for (int c = 0; c < Cch; c++) ch[c] = cp[(size_t)c*HW];

  // sem_pred: argmax over 10 raw channels, first-index ties
  int smp = 0; float smv = ch[0];
#pragma unroll
  for (int c = 1; c < Cch; c++) if (ch[c] > smv) { smv = ch[c]; smp = c; }

  // po argmax: stuff channels first (f64 domain)
  double m = (double)ch[0]; int pidx = 0;
#pragma unroll
  for (int c = 1; c < NSs; c++) { double v = (double)ch[c]; if (v > m) { m = v; pidx = c; } }

  const double EPS = (sigd(NEGD) + sigd(NEGD)) * (NEGD + NEGD); // value for any non-covering instance

  unsigned rel = s_rel;
  int next_ch = NSs;
  while (rel) {
    int n = __ffs(rel) - 1; rel &= rel - 1;
    int chn = NSs + n;
    // run of irrelevant channels [next_ch, chn): all exactly EPS
    if (chn > next_ch && EPS > m) { m = EPS; pidx = next_ch; }
    const InstP p = spar[n];
    bool in_i = (y >= p.y0) && (y < p.y1r) && (x >= p.x0) && (x < p.x1r);
    bool in_m = (y >= p.ys) && (y < p.ye)  && (x >= p.xs) && (x < p.xe);
    double val;
    if (in_i | in_m) {
      double iv = in_i ? (double)ch[p.tc] : NEGD;
      double mv;
      if (in_m) {
        double syv = ((double)(y - p.y0) + 0.5) * (double)p.sc_y - 0.5;
        double sxv = ((double)(x - p.x0) + 0.5) * (double)p.sc_x - 0.5;
        syv = fmin(fmax(syv, 0.0), 27.0);
        sxv = fmin(fmax(sxv, 0.0), 27.0);
        int iy0 = (int)syv, ix0 = (int)sxv;
        int iy1 = min(iy0 + 1, 27), ix1 = min(ix0 + 1, 27);
        double wy = syv - (double)iy0, wx = sxv - (double)ix0;
        const float* mp = roi + p.mskoff;
        double m00 = (double)mp[iy0*Rr + ix0];
        double m01 = (double)mp[iy0*Rr + ix1];
        double m10 = (double)mp[iy1*Rr + ix0];
        double m11 = (double)mp[iy1*Rr + ix1];
        double c0 = m00*(1.0 - wy) + m10*wy;
        double c1 = m01*(1.0 - wy) + m11*wy;
        mv = c0*(1.0 - wx) + c1*wx;
      } else mv = NEGD;
      val = (sigd(iv) + sigd(mv)) * (iv + mv);
    } else val = EPS;
    if (val > m) { m = val; pidx = chn; }
    next_ch = chn + 1;
  }
  if (next_ch < NCH && EPS > m) { m = EPS; pidx = next_ch; }

  out_pred[(size_t)b*HW + (size_t)y*Ww + x] = pidx;

  if (pidx >= NSs) atomicAdd(&s_hist[(pidx - NSs)*Cch + smp], 1);
  else             atomicAdd(&s_sc[pidx], 1);

  __syncthreads();
  for (int i = tid; i < Nn*Cch; i += 256) {
    int v = s_hist[i];
    if (v) atomicAdd(&g_hist[b*Nn*Cch + i], v);
  }
  if (tid < NSs) {
    int v = s_sc[tid];
    if (v) atomicAdd(&g_scount[b*NSs + tid], v);
  }
}

// one block; thread b (b<2) does the whole per-batch post logic serially (tiny)
__global__ void k_post(const int* __restrict__ g_hist, const int* __restrict__ g_scount,
                       const int* __restrict__ cls, int* __restrict__ lut,
                       int* __restrict__ out_tail)
{
  int b = threadIdx.x;
  if (b >= Bb) return;
  const int* hb = g_hist + b*Nn*Cch;
  int total[Nn], semmax[Nn], tmp[Nn], rank_k[Nn];
  bool br2[Nn], kept[Nn];
  for (int n = 0; n < Nn; n++) {
    int t = 0, mx = -1, mi = 0;
    for (int c = 0; c < Cch; c++) {
      int v = hb[n*Cch + c]; t += v;
      if (v > mx) { mx = v; mi = c; }
    }
    total[n] = t; semmax[n] = mi;
    tmp[n] = cls[b*Nn + n] + NSs;
    bool present = t > 0;
    bool b1 = (mi == tmp[n]);
    br2[n]  = (!b1) && (2*mx >= t) && (mi < NSs) && present;
    kept[n] = present && !br2[n];
  }
  int spc[NSs];
  for (int s = 0; s < NSs; s++) spc[s] = g_scount[b*NSs + s];
  for (int n = 0; n < Nn; n++) if (br2[n]) spc[semmax[n]] += total[n];
  int srank[NSs]; int nstuff = 0;
  for (int s = 0; s < NSs; s++) {
    if (spc[s] > 0) { srank[s] = nstuff; nstuff++; }
    else srank[s] = nstuff - 1;          // cumsum-1 semantics (unused when absent)
  }
  int nk = 0;
  for (int n = 0; n < Nn; n++) { if (kept[n]) { rank_k[n] = nk; nk++; } else rank_k[n] = -1; }

  int* lb = lut + b*NCH;
  for (int s = 0; s < NSs; s++) lb[s] = srank[s] + 1;
  for (int n = 0; n < Nn; n++)
    lb[NSs + n] = kept[n] ? (1 + nstuff + rank_k[n])
                          : (br2[n] ? srank[semmax[n]] + 1 : 0);

  int* pc = out_tail;                  // po_cls   [Bb][39]
  int* ic = out_tail + Bb*39;          // iscrowd  [Bb][39]
  int* vl = out_tail + 2*Bb*39;        // valid_len[Bb]
  for (int i = 0; i < 39; i++) pc[b*39 + i] = -1;
  pc[b*39 + 0] = 255;
  for (int s = 0; s < NSs; s++) if (spc[s] > 0) pc[b*39 + 1 + srank[s]] = s;
  for (int n = 0; n < Nn; n++) if (kept[n])    pc[b*39 + 1 + nstuff + rank_k[n]] = tmp[n];
  int vlen = 1 + nstuff + nk;
  vl[b] = vlen;
  for (int i = 0; i < 39; i++) ic[b*39 + i] = (i < vlen) ? 0 : -1;
}

__global__ __launch_bounds__(256) void k_seam(int* __restrict__ pred, const int* __restrict__ lut)
{
  __shared__ int slut[Bb*NCH];
  int tid = threadIdx.x;
  if (tid < Bb*NCH) slut[tid] = lut[tid];
  __syncthreads();
  size_t i = ((size_t)blockIdx.x*256 + tid) * 4;
  int b = (int)(i / HW);   // HW divisible by 4: no straddle
  int4 v = *reinterpret_cast<int4*>(pred + i);
  int base = b*NCH;
  v.x = slut[base + v.x];
  v.y = slut[base + v.y];
  v.z = slut[base + v.z];
  v.w = slut[base + v.w];
  *reinterpret_cast<int4*>(pred + i) = v;
}

extern "C" void kernel_launch(void* const* d_in, const int* in_sizes, int n_in,
                              void* d_out, int out_size, void* d_ws, size_t ws_size,
                              hipStream_t stream)
{
  const float* sem = (const float*)d_in[0];
  const float* roi = (const float*)d_in[1];
  const float* bbx = (const float*)d_in[2];
  const int*   cls = (const int*)d_in[3];
  int* out = (int*)d_out;

  int* g_hist   = (int*)d_ws;                 // Bb*Nn*Cch = 640
  int* g_scount = g_hist + Bb*Nn*Cch;         // Bb*NSs   = 12
  int* lut      = g_scount + Bb*NSs;          // Bb*NCH   = 76

  k_zero<<<1, 256, 0, stream>>>(g_hist, Bb*Nn*Cch + Bb*NSs);
  k_fuse<<<dim3(Bb*Hh*(Ww/256)), 256, 0, stream>>>(sem, roi, bbx, cls, out, g_hist, g_scount);
  k_post<<<1, 64, 0, stream>>>(g_hist, g_scount, cls, lut, out + (size_t)Bb*HW);
  k_seam<<<dim3((Bb*HW)/(256*4)), 256, 0, stream>>>(out, lut);
}

// Round 2
// 153.471 us; speedup vs baseline: 1.1070x; 1.1070x over previous
//
#include <hip/hip_runtime.h>
#include <math.h>

#define NSs 6
#define NTs 4
#define Bb  2
#define Nn  32
#define Hh  768
#define Ww  768
#define Rr  28
#define Cch 10
#define NCH 38
#define HW  (Hh*Ww)
#define NEGD (-100.0)
#define NKEY (Nn*Cch + NSs)   // combined hist keys: 320 inst-hist + 6 stuff counts

struct InstP {
  int y0, x0, y1r, x1r;   // inst box [y0,y1r) x [x0,x1r)
  int ys, ye, xs, xe;     // mask box
  float sc_y, sc_x;       // 28.f/h, 28.f/w  (f32 to match ref's R/h)
  int tc;                 // NS + cls  (thing channel)
  int mskoff;             // element offset of selected 28x28 mask
};

__device__ __forceinline__ double sigd(double x) { return 1.0 / (1.0 + exp(-x)); }

__global__ void k_zero(int* __restrict__ p, int n) {
  for (int i = threadIdx.x; i < n; i += 256) p[i] = 0;
}

__global__ __launch_bounds__(256) void k_fuse(
    const float* __restrict__ sem, const float* __restrict__ roi,
    const float* __restrict__ bbx, const int* __restrict__ cls,
    int* __restrict__ out_pred, int* __restrict__ g_hist, int* __restrict__ g_scount)
{
  __shared__ InstP spar[Nn];
  __shared__ int s_all[NKEY];
  __shared__ unsigned s_rel;

  const int bid  = blockIdx.x;
  const int xseg = bid % (Ww/256);
  const int y    = (bid / (Ww/256)) % Hh;
  const int b    = bid / ((Ww/256)*Hh);
  const int x0b  = xseg * 256;
  const int tid  = threadIdx.x;

  if (tid == 0) s_rel = 0u;
  for (int i = tid; i < NKEY; i += 256) s_all[i] = 0;
  if (tid < Nn) {
    const int n = tid;
    const float* bbp = bbx + ((size_t)b*Nn + n)*4;
    float f0 = bbp[0], f1 = bbp[1], f2 = bbp[2], f3 = bbp[3];
    int y0 = (int)floorf(f0), x0 = (int)floorf(f1);
    int y1 = (int)floorf(f2), x1 = (int)floorf(f3);
    int y1r = (int)(rintf(f2) + 1.0f);   // jnp.round = half-to-even
    int x1r = (int)(rintf(f3) + 1.0f);
    float hh = fmaxf((float)(y1 - y0 + 1), 1.0f);
    float wd = fmaxf((float)(x1 - x0 + 1), 1.0f);
    InstP p;
    p.y0 = y0; p.x0 = x0; p.y1r = y1r; p.x1r = x1r;
    p.ys = max(y0, 0); p.ye = min(y1 + 1, Hh);
    p.xs = max(x0, 0); p.xe = min(x1 + 1, Ww);
    p.sc_y = 28.0f / hh; p.sc_x = 28.0f / wd;
    int cl = cls[b*Nn + n];
    p.tc = NSs + cl;
    p.mskoff = (((b*Nn + n)*NTs) + cl)*Rr*Rr;
    spar[n] = p;
    bool rel_i = (y >= y0)   && (y < y1r)  && (x0   <= x0b + 255) && (x1r  > x0b);
    bool rel_m = (y >= p.ys) && (y < p.ye) && (p.xs <= x0b + 255) && (p.xe > x0b);
    if (rel_i || rel_m) atomicOr(&s_rel, 1u << n);
  }
  __syncthreads();

  const int x = x0b + tid;
  const float* cp = sem + (size_t)b*Cch*HW + (size_t)y*Ww + x;
  float ch[Cch];
#pragma unroll
  for (int c = 0; c < Cch; c++) ch[c] = cp[(size_t)c*HW];

  // sem_pred: argmax over 10 raw channels, first-index ties
  int smp = 0; float smv = ch[0];
#pragma unroll
  for (int c = 1; c < Cch; c++) if (ch[c] > smv) { smv = ch[c]; smp = c; }

  // po argmax: stuff channels first (f64 domain)
  double m = (double)ch[0]; int pidx = 0;
#pragma unroll
  for (int c = 1; c < NSs; c++) { double v = (double)ch[c]; if (v > m) { m = v; pidx = c; } }

  const double EPS = (sigd(NEGD) + sigd(NEGD)) * (NEGD + NEGD); // value for any non-covering instance

  unsigned rel = s_rel;
  int next_ch = NSs;
  while (rel) {
    int n = __ffs(rel) - 1; rel &= rel - 1;
    int chn = NSs + n;
    // run of irrelevant channels [next_ch, chn): all exactly EPS
    if (chn > next_ch && EPS > m) { m = EPS; pidx = next_ch; }
    const InstP p = spar[n];
    bool in_i = (y >= p.y0) && (y < p.y1r) && (x >= p.x0) && (x < p.x1r);
    bool in_m = (y >= p.ys) && (y < p.ye)  && (x >= p.xs) && (x < p.xe);
    double val;
    if (in_i | in_m) {
      // select chain (NOT ch[p.tc]): dynamic register-array indexing demotes
      // ch[] to scratch (R1: VGPR_Count=20, k_fuse 62us latency-bound)
      int tcl = p.tc;
      float tl = (tcl == 6) ? ch[6] : (tcl == 7) ? ch[7] : (tcl == 8) ? ch[8] : ch[9];
      double iv = in_i ? (double)tl : NEGD;
      double mv;
      if (in_m) {
        double syv = ((double)(y - p.y0) + 0.5) * (double)p.sc_y - 0.5;
        double sxv = ((double)(x - p.x0) + 0.5) * (double)p.sc_x - 0.5;
        syv = fmin(fmax(syv, 0.0), 27.0);
        sxv = fmin(fmax(sxv, 0.0), 27.0);
        int iy0 = (int)syv, ix0 = (int)sxv;
        int iy1 = min(iy0 + 1, 27), ix1 = min(ix0 + 1, 27);
        double wy = syv - (double)iy0, wx = sxv - (double)ix0;
        const float* mp = roi + p.mskoff;
        double m00 = (double)mp[iy0*Rr + ix0];
        double m01 = (double)mp[iy0*Rr + ix1];
        double m10 = (double)mp[iy1*Rr + ix0];
        double m11 = (double)mp[iy1*Rr + ix1];
        double c0 = m00*(1.0 - wy) + m10*wy;
        double c1 = m01*(1.0 - wy) + m11*wy;
        mv = c0*(1.0 - wx) + c1*wx;
      } else mv = NEGD;
      val = (sigd(iv) + sigd(mv)) * (iv + mv);
    } else val = EPS;
    if (val > m) { m = val; pidx = chn; }
    next_ch = chn + 1;
  }
  if (next_ch < NCH && EPS > m) { m = EPS; pidx = next_ch; }

  out_pred[(size_t)b*HW + (size_t)y*Ww + x] = pidx;

  // wave-aggregated histogram update: few distinct keys per wave -> few LDS atomics
  {
    int key = (pidx >= NSs) ? ((pidx - NSs)*Cch + smp) : (Nn*Cch + pidx);
    unsigned long long remaining = __ballot(1);
    while (remaining) {
      int leader = __ffsll(remaining) - 1;
      int lkey = __shfl(key, leader, 64);
      unsigned long long same = __ballot(key == lkey) & remaining;
      if ((tid & 63) == leader)
        atomicAdd(&s_all[lkey], (int)__builtin_popcountll(same));
      remaining &= ~same;
    }
  }

  __syncthreads();
  for (int i = tid; i < NKEY; i += 256) {
    int v = s_all[i];
    if (v) {
      if (i < Nn*Cch) atomicAdd(&g_hist[b*Nn*Cch + i], v);
      else            atomicAdd(&g_scount[b*NSs + (i - Nn*Cch)], v);
    }
  }
}

// one block of 256: cooperative LDS staging, then 2 threads do per-batch serial logic
__global__ __launch_bounds__(256) void k_post(
    const int* __restrict__ g_hist, const int* __restrict__ g_scount,
    const int* __restrict__ cls, int* __restrict__ lut,
    int* __restrict__ out_tail)
{
  __shared__ int sh[Bb*Nn*Cch];
  __shared__ int ssc[Bb*NSs];
  __shared__ int scl[Bb*Nn];
  int t = threadIdx.x;
  for (int i = t; i < Bb*Nn*Cch; i += 256) sh[i] = g_hist[i];
  if (t < Bb*NSs) ssc[t] = g_scount[t];
  if (t < Bb*Nn)  scl[t] = cls[t];
  __syncthreads();
  int b = t;
  if (b >= Bb) return;
  const int* hb = sh + b*Nn*Cch;
  int total[Nn], semmax[Nn], tmp[Nn], rank_k[Nn];
  bool br2[Nn], kept[Nn];
  for (int n = 0; n < Nn; n++) {
    int tt = 0, mx = -1, mi = 0;
#pragma unroll
    for (int c = 0; c < Cch; c++) {
      int v = hb[n*Cch + c]; tt += v;
      if (v > mx) { mx = v; mi = c; }
    }
    total[n] = tt; semmax[n] = mi;
    tmp[n] = scl[b*Nn + n] + NSs;
    bool present = tt > 0;
    bool b1 = (mi == tmp[n]);
    br2[n]  = (!b1) && (2*mx >= tt) && (mi < NSs) && present;
    kept[n] = present && !br2[n];
  }
  int spc[NSs];
#pragma unroll
  for (int s = 0; s < NSs; s++) spc[s] = ssc[b*NSs + s];
  for (int n = 0; n < Nn; n++) if (br2[n]) spc[semmax[n]] += total[n];
  int srank[NSs]; int nstuff = 0;
#pragma unroll
  for (int s = 0; s < NSs; s++) {
    if (spc[s] > 0) { srank[s] = nstuff; nstuff++; }
    else srank[s] = nstuff - 1;          // cumsum-1 semantics (unused when absent)
  }
  int nk = 0;
  for (int n = 0; n < Nn; n++) { if (kept[n]) { rank_k[n] = nk; nk++; } else rank_k[n] = -1; }

  int* lb = lut + b*NCH;
#pragma unroll
  for (int s = 0; s < NSs; s++) lb[s] = srank[s] + 1;
  for (int n = 0; n < Nn; n++)
    lb[NSs + n] = kept[n] ? (1 + nstuff + rank_k[n])
                          : (br2[n] ? srank[semmax[n]] + 1 : 0);

  int* pc = out_tail;                  // po_cls   [Bb][39]
  int* ic = out_tail + Bb*39;          // iscrowd  [Bb][39]
  int* vl = out_tail + 2*Bb*39;        // valid_len[Bb]
  for (int i = 0; i < 39; i++) pc[b*39 + i] = -1;
  pc[b*39 + 0] = 255;
#pragma unroll
  for (int s = 0; s < NSs; s++) if (spc[s] > 0) pc[b*39 + 1 + srank[s]] = s;
  for (int n = 0; n < Nn; n++) if (kept[n])    pc[b*39 + 1 + nstuff + rank_k[n]] = tmp[n];
  int vlen = 1 + nstuff + nk;
  vl[b] = vlen;
  for (int i = 0; i < 39; i++) ic[b*39 + i] = (i < vlen) ? 0 : -1;
}

__global__ __launch_bounds__(256) void k_seam(int* __restrict__ pred, const int* __restrict__ lut)
{
  __shared__ int slut[Bb*NCH];
  int tid = threadIdx.x;
  if (tid < Bb*NCH) slut[tid] = lut[tid];
  __syncthreads();
  size_t i = ((size_t)blockIdx.x*256 + tid) * 4;
  int b = (int)(i / HW);   // HW divisible by 4: no straddle
  int4 v = *reinterpret_cast<int4*>(pred + i);
  int base = b*NCH;
  v.x = slut[base + v.x];
  v.y = slut[base + v.y];
  v.z = slut[base + v.z];
  v.w = slut[base + v.w];
  *reinterpret_cast<int4*>(pred + i) = v;
}

extern "C" void kernel_launch(void* const* d_in, const int* in_sizes, int n_in,
                              void* d_out, int out_size, void* d_ws, size_t ws_size,
                              hipStream_t stream)
{
  const float* sem = (const float*)d_in[0];
  const float* roi = (const float*)d_in[1];
  const float* bbx = (const float*)d_in[2];
  const int*   cls = (const int*)d_in[3];
  int* out = (int*)d_out;

  int* g_hist   = (int*)d_ws;                 // Bb*Nn*Cch = 640
  int* g_scount = g_hist + Bb*Nn*Cch;         // Bb*NSs   = 12
  int* lut      = g_scount + Bb*NSs;          // Bb*NCH   = 76

  k_zero<<<1, 256, 0, stream>>>(g_hist, Bb*Nn*Cch + Bb*NSs);
  k_fuse<<<dim3(Bb*Hh*(Ww/256)), 256, 0, stream>>>(sem, roi, bbx, cls, out, g_hist, g_scount);
  k_post<<<1, 256, 0, stream>>>(g_hist, g_scount, cls, lut, out + (size_t)Bb*HW);
  k_seam<<<dim3((Bb*HW)/(256*4)), 256, 0, stream>>>(out, lut);
}

// Round 4
// 149.377 us; speedup vs baseline: 1.1374x; 1.0274x over previous
//
#include <hip/hip_runtime.h>
#include <math.h>

#define NSs 6
#define NTs 4
#define Bb  2
#define Nn  32
#define Hh  768
#define Ww  768
#define Rr  28
#define Cch 10
#define NCH 38
#define HW  (Hh*Ww)
#define NEGD (-100.0)
#define NKEY (Nn*Cch + NSs)   // 320 inst-hist keys + 6 stuff counts

struct InstP {
  int y0, x0, y1r, x1r;   // inst box [y0,y1r) x [x0,x1r)
  int ys, ye, xs, xe;     // mask box
  float sc_y, sc_x;       // 28.f/h, 28.f/w
  int tc;                 // NS + cls
  int mskoff;             // offset of selected 28x28 mask
};

__device__ __forceinline__ double sigd(double x) { return 1.0 / (1.0 + exp(-x)); }

__global__ void k_zero(int* __restrict__ p, int n) {
  for (int i = threadIdx.x; i < n; i += 256) p[i] = 0;
}

// 576 blocks = 2 batches x 96 ytiles x 3 xsegs; each block does a 256-wide x 8-tall tile.
// Per-block setup/flush amortized 8x vs R2's 1-row blocks; next-row channel prefetch
// gives ~10 outstanding loads per wave overlapped with current-row compute.
__global__ __launch_bounds__(256) void k_fuse(
    const float* __restrict__ sem, const float* __restrict__ roi,
    const float* __restrict__ bbx, const int* __restrict__ cls,
    int* __restrict__ out_pred, int* __restrict__ g_hist, int* __restrict__ g_scount)
{
  __shared__ InstP spar[Nn];
  __shared__ int s_all[NKEY];
  __shared__ unsigned s_relrow[8];

  const int bid   = blockIdx.x;
  const int xseg  = bid % 3;
  const int yt    = (bid / 3) % 96;
  const int b     = bid / (3*96);
  const int x0b   = xseg * 256;
  const int ybase = yt * 8;
  const int tid   = threadIdx.x;
  const int x     = x0b + tid;

  if (tid < 8) s_relrow[tid] = 0u;     // same wave as the atomicOr below: program order safe
  for (int i = tid; i < NKEY; i += 256) s_all[i] = 0;
  if (tid < Nn) {
    const int n = tid;
    const float* bbp = bbx + ((size_t)b*Nn + n)*4;
    float f0 = bbp[0], f1 = bbp[1], f2 = bbp[2], f3 = bbp[3];
    int y0 = (int)floorf(f0), x0 = (int)floorf(f1);
    int y1 = (int)floorf(f2), x1 = (int)floorf(f3);
    int y1r = (int)(rintf(f2) + 1.0f);   // jnp.round = half-to-even
    int x1r = (int)(rintf(f3) + 1.0f);
    float hh = fmaxf((float)(y1 - y0 + 1), 1.0f);
    float wd = fmaxf((float)(x1 - x0 + 1), 1.0f);
    InstP p;
    p.y0 = y0; p.x0 = x0; p.y1r = y1r; p.x1r = x1r;
    p.ys = max(y0, 0); p.ye = min(y1 + 1, Hh);
    p.xs = max(x0, 0); p.xe = min(x1 + 1, Ww);
    p.sc_y = 28.0f / hh; p.sc_x = 28.0f / wd;
    int cl = cls[b*Nn + n];
    p.tc = NSs + cl;
    p.mskoff = (((b*Nn + n)*NTs) + cl)*Rr*Rr;
    spar[n] = p;
    bool colI = (x0   <= x0b + 255) && (x1r  > x0b);
    bool colM = (p.xs <= x0b + 255) && (p.xe > x0b);
    for (int iy = 0; iy < 8; iy++) {
      int y = ybase + iy;
      bool rowi = (y >= y0)   && (y < y1r);
      bool rowm = (y >= p.ys) && (y < p.ye);
      if ((rowi && colI) || (rowm && colM)) atomicOr(&s_relrow[iy], 1u << n);
    }
  }
  __syncthreads();

  const double EPS = (sigd(NEGD) + sigd(NEGD)) * (NEGD + NEGD);
  const float* cp0 = sem + (size_t)b*Cch*HW + (size_t)ybase*Ww + x;

  float chn[Cch];
#pragma unroll
  for (int c = 0; c < Cch; c++) chn[c] = cp0[(size_t)c*HW];

  for (int iy = 0; iy < 8; iy++) {
    float ch[Cch];
#pragma unroll
    for (int c = 0; c < Cch; c++) ch[c] = chn[c];
    if (iy < 7) {   // prefetch next row while computing this one
      const float* cpn = cp0 + (size_t)(iy+1)*Ww;
#pragma unroll
      for (int c = 0; c < Cch; c++) chn[c] = cpn[(size_t)c*HW];
    }
    const int y = ybase + iy;

    int smp = 0; float smv = ch[0];
#pragma unroll
    for (int c = 1; c < Cch; c++) if (ch[c] > smv) { smv = ch[c]; smp = c; }

    double m = (double)ch[0]; int pidx = 0;
#pragma unroll
    for (int c = 1; c < NSs; c++) { double v = (double)ch[c]; if (v > m) { m = v; pidx = c; } }

    unsigned rel = s_relrow[iy];
    int next_ch = NSs;
    while (rel) {
      int n = __ffs(rel) - 1; rel &= rel - 1;
      int chn_ = NSs + n;
      if (chn_ > next_ch && EPS > m) { m = EPS; pidx = next_ch; }
      next_ch = chn_ + 1;
      const InstP p = spar[n];
      bool in_i = (y >= p.y0) && (y < p.y1r) && (x >= p.x0) && (x < p.x1r);
      bool in_m = (y >= p.ys) && (y < p.ye)  && (x >= p.xs) && (x < p.xe);
      bool in_any = in_i || in_m;
      if (in_any) {
        // select chain (NOT ch[p.tc]): dynamic reg-array indexing demotes to scratch
        int tcl = p.tc;
        float tl = (tcl == 6) ? ch[6] : (tcl == 7) ? ch[7] : (tcl == 8) ? ch[8] : ch[9];
        double iv = in_i ? (double)tl : NEGD;
        double mv = NEGD;
        if (in_m) {
          double syv = ((double)(y - p.y0) + 0.5) * (double)p.sc_y - 0.5;
          double sxv = ((double)(x - p.x0) + 0.5) * (double)p.sc_x - 0.5;
          syv = fmin(fmax(syv, 0.0), 27.0);
          sxv = fmin(fmax(sxv, 0.0), 27.0);
          int iy0 = (int)syv, ix0 = (int)sxv;
          int iy1 = min(iy0 + 1, 27), ix1 = min(ix0 + 1, 27);
          double wy = syv - (double)iy0, wx = sxv - (double)ix0;
          const float* mp = roi + p.mskoff;
          double m00 = (double)mp[iy0*Rr + ix0];
          double m01 = (double)mp[iy0*Rr + ix1];
          double m10 = (double)mp[iy1*Rr + ix0];
          double m11 = (double)mp[iy1*Rr + ix1];
          double c0 = m00*(1.0 - wy) + m10*wy;
          double c1 = m01*(1.0 - wy) + m11*wy;
          mv = c0*(1.0 - wx) + c1*wx;
        }
        double s2 = iv + mv;
        // prune: val = s*s2 with s in (0,2]; if fmax(2*s2,0) <= m then val > m
        // is impossible (monotone rounding, 2*s2 exact) -> skip both f64 exps
        if (fmax(2.0*s2, 0.0) > m) {
          double val = (sigd(iv) + sigd(mv)) * s2;
          if (val > m) { m = val; pidx = chn_; }
        }
      } else {
        if (EPS > m) { m = EPS; pidx = chn_; }
      }
    }
    if (next_ch < NCH && EPS > m) { m = EPS; pidx = next_ch; }

    out_pred[(size_t)b*HW + (size_t)y*Ww + x] = pidx;
    int key = (pidx >= NSs) ? ((pidx - NSs)*Cch + smp) : (Nn*Cch + pidx);
    atomicAdd(&s_all[key], 1);
  }

  __syncthreads();
  for (int i = tid; i < NKEY; i += 256) {
    int v = s_all[i];
    if (v) {
      if (i < Nn*Cch) atomicAdd(&g_hist[b*Nn*Cch + i], v);
      else            atomicAdd(&g_scount[b*NSs + (i - Nn*Cch)], v);
    }
  }
}

// one block of 256: cooperative LDS staging, then 2 threads do per-batch serial logic
__global__ __launch_bounds__(256) void k_post(
    const int* __restrict__ g_hist, const int* __restrict__ g_scount,
    const int* __restrict__ cls, int* __restrict__ lut,
    int* __restrict__ out_tail)
{
  __shared__ int sh[Bb*Nn*Cch];
  __shared__ int ssc[Bb*NSs];
  __shared__ int scl[Bb*Nn];
  int t = threadIdx.x;
  for (int i = t; i < Bb*Nn*Cch; i += 256) sh[i] = g_hist[i];
  if (t < Bb*NSs) ssc[t] = g_scount[t];
  if (t < Bb*Nn)  scl[t] = cls[t];
  __syncthreads();
  int b = t;
  if (b >= Bb) return;
  const int* hb = sh + b*Nn*Cch;
  int total[Nn], semmax[Nn], tmp[Nn], rank_k[Nn];
  bool br2[Nn], kept[Nn];
  for (int n = 0; n < Nn; n++) {
    int tt = 0, mx = -1, mi = 0;
#pragma unroll
    for (int c = 0; c < Cch; c++) {
      int v = hb[n*Cch + c]; tt += v;
      if (v > mx) { mx = v; mi = c; }
    }
    total[n] = tt; semmax[n] = mi;
    tmp[n] = scl[b*Nn + n] + NSs;
    bool present = tt > 0;
    bool b1 = (mi == tmp[n]);
    br2[n]  = (!b1) && (2*mx >= tt) && (mi < NSs) && present;
    kept[n] = present && !br2[n];
  }
  int spc[NSs];
#pragma unroll
  for (int s = 0; s < NSs; s++) spc[s] = ssc[b*NSs + s];
  for (int n = 0; n < Nn; n++) if (br2[n]) spc[semmax[n]] += total[n];
  int srank[NSs]; int nstuff = 0;
#pragma unroll
  for (int s = 0; s < NSs; s++) {
    if (spc[s] > 0) { srank[s] = nstuff; nstuff++; }
    else srank[s] = nstuff - 1;          // cumsum-1 semantics (unused when absent)
  }
  int nk = 0;
  for (int n = 0; n < Nn; n++) { if (kept[n]) { rank_k[n] = nk; nk++; } else rank_k[n] = -1; }

  int* lb = lut + b*NCH;
#pragma unroll
  for (int s = 0; s < NSs; s++) lb[s] = srank[s] + 1;
  for (int n = 0; n < Nn; n++)
    lb[NSs + n] = kept[n] ? (1 + nstuff + rank_k[n])
                          : (br2[n] ? srank[semmax[n]] + 1 : 0);

  int* pc = out_tail;                  // po_cls   [Bb][39]
  int* ic = out_tail + Bb*39;          // iscrowd  [Bb][39]
  int* vl = out_tail + 2*Bb*39;        // valid_len[Bb]
  for (int i = 0; i < 39; i++) pc[b*39 + i] = -1;
  pc[b*39 + 0] = 255;
#pragma unroll
  for (int s = 0; s < NSs; s++) if (spc[s] > 0) pc[b*39 + 1 + srank[s]] = s;
  for (int n = 0; n < Nn; n++) if (kept[n])    pc[b*39 + 1 + nstuff + rank_k[n]] = tmp[n];
  int vlen = 1 + nstuff + nk;
  vl[b] = vlen;
  for (int i = 0; i < 39; i++) ic[b*39 + i] = (i < vlen) ? 0 : -1;
}

__global__ __launch_bounds__(256) void k_seam(int* __restrict__ pred, const int* __restrict__ lut)
{
  __shared__ int slut[Bb*NCH];
  int tid = threadIdx.x;
  if (tid < Bb*NCH) slut[tid] = lut[tid];
  __syncthreads();
  size_t i = ((size_t)blockIdx.x*256 + tid) * 4;
  int b = (int)(i / HW);   // HW divisible by 4: no straddle
  int4 v = *reinterpret_cast<int4*>(pred + i);
  int base = b*NCH;
  v.x = slut[base + v.x];
  v.y = slut[base + v.y];
  v.z = slut[base + v.z];
  v.w = slut[base + v.w];
  *reinterpret_cast<int4*>(pred + i) = v;
}

extern "C" void kernel_launch(void* const* d_in, const int* in_sizes, int n_in,
                              void* d_out, int out_size, void* d_ws, size_t ws_size,
                              hipStream_t stream)
{
  const float* sem = (const float*)d_in[0];
  const float* roi = (const float*)d_in[1];
  const float* bbx = (const float*)d_in[2];
  const int*   cls = (const int*)d_in[3];
  int* out = (int*)d_out;

  int* g_hist   = (int*)d_ws;                 // Bb*Nn*Cch = 640
  int* g_scount = g_hist + Bb*Nn*Cch;         // Bb*NSs   = 12
  int* lut      = g_scount + Bb*NSs;          // Bb*NCH   = 76

  k_zero<<<1, 256, 0, stream>>>(g_hist, Bb*Nn*Cch + Bb*NSs);
  k_fuse<<<dim3(Bb*96*3), 256, 0, stream>>>(sem, roi, bbx, cls, out, g_hist, g_scount);
  k_post<<<1, 256, 0, stream>>>(g_hist, g_scount, cls, lut, out + (size_t)Bb*HW);
  k_seam<<<dim3((Bb*HW)/(256*4)), 256, 0, stream>>>(out, lut);
}

// Round 5
// 113.066 us; speedup vs baseline: 1.5026x; 1.3211x over previous
//
#include <hip/hip_runtime.h>
#include <math.h>

#define NSs 6
#define NTs 4
#define Bb  2
#define Nn  32
#define Hh  768
#define Ww  768
#define Rr  28
#define Cch 10
#define NCH 38
#define HW  (Hh*Ww)
#define NEGD (-100.0)
#define NKEY (Nn*Cch + NSs)   // 320 inst-hist keys + 6 stuff counts

struct InstP {
  int y0, x0, y1r, x1r;   // inst box [y0,y1r) x [x0,x1r)
  int ys, ye, xs, xe;     // mask box
  float sc_y, sc_x;       // 28.f/h, 28.f/w
  int tc;                 // NS + cls
  int mskoff;             // offset of selected 28x28 mask
};

__device__ __forceinline__ double sigd(double x) { return 1.0 / (1.0 + exp(-x)); }

__global__ void k_zero(int* __restrict__ p, int n) {
  for (int i = threadIdx.x; i < n; i += 256) p[i] = 0;
}

// per-pixel fuse+argmax. ch[] must be constant-indexed after inlining.
__device__ __forceinline__ void do_px(
    int b, int y, int x, const float (&ch)[Cch], unsigned rel,
    const InstP* __restrict__ spar, const float* __restrict__ roi,
    int* __restrict__ out_pred, int* __restrict__ s_all, double EPS)
{
  int smp = 0; float smv = ch[0];
#pragma unroll
  for (int c = 1; c < Cch; c++) if (ch[c] > smv) { smv = ch[c]; smp = c; }

  double m = (double)ch[0]; int pidx = 0;
#pragma unroll
  for (int c = 1; c < NSs; c++) { double v = (double)ch[c]; if (v > m) { m = v; pidx = c; } }

  int next_ch = NSs;
  while (rel) {
    int n = __ffs(rel) - 1; rel &= rel - 1;
    int chn_ = NSs + n;
    if (chn_ > next_ch && EPS > m) { m = EPS; pidx = next_ch; }
    next_ch = chn_ + 1;
    const InstP p = spar[n];
    bool in_i = (y >= p.y0) && (y < p.y1r) && (x >= p.x0) && (x < p.x1r);
    bool in_m = (y >= p.ys) && (y < p.ye)  && (x >= p.xs) && (x < p.xe);
    bool in_any = in_i || in_m;
    if (__any(in_any)) {            // wave lanes = contiguous 64-px window
      if (in_any) {
        // select chain (NOT ch[p.tc]): dynamic reg-array indexing -> scratch
        int tcl = p.tc;
        float tl = (tcl == 6) ? ch[6] : (tcl == 7) ? ch[7] : (tcl == 8) ? ch[8] : ch[9];
        double iv = in_i ? (double)tl : NEGD;
        double mv = NEGD;
        if (in_m) {
          double syv = ((double)(y - p.y0) + 0.5) * (double)p.sc_y - 0.5;
          double sxv = ((double)(x - p.x0) + 0.5) * (double)p.sc_x - 0.5;
          syv = fmin(fmax(syv, 0.0), 27.0);
          sxv = fmin(fmax(sxv, 0.0), 27.0);
          int iy0 = (int)syv, ix0 = (int)sxv;
          int iy1 = min(iy0 + 1, 27), ix1 = min(ix0 + 1, 27);
          double wy = syv - (double)iy0, wx = sxv - (double)ix0;
          const float* mp = roi + p.mskoff;
          double m00 = (double)mp[iy0*Rr + ix0];
          double m01 = (double)mp[iy0*Rr + ix1];
          double m10 = (double)mp[iy1*Rr + ix0];
          double m11 = (double)mp[iy1*Rr + ix1];
          double c0 = m00*(1.0 - wy) + m10*wy;
          double c1 = m01*(1.0 - wy) + m11*wy;
          mv = c0*(1.0 - wx) + c1*wx;
        }
        double s2 = iv + mv;
        // prune: val = s*s2, s in (0,2]; if fmax(2*s2,0) <= m, val>m impossible
        if (fmax(2.0*s2, 0.0) > m) {
          double val = (sigd(iv) + sigd(mv)) * s2;
          if (val > m) { m = val; pidx = chn_; }
        }
      } else {
        if (EPS > m) { m = EPS; pidx = chn_; }
      }
    } else {
      if (EPS > m) { m = EPS; pidx = chn_; }
    }
  }
  if (next_ch < NCH && EPS > m) { m = EPS; pidx = next_ch; }

  out_pred[(size_t)b*HW + (size_t)y*Ww + x] = pidx;
  int key = (pidx >= NSs) ? ((pidx - NSs)*Cch + smp) : (Nn*Cch + pidx);
  atomicAdd(&s_all[key], 1);
}

// grid = B*H = 1536 full-row blocks; 256 threads x 3 px (stride 256).
// Rows are load-uniform -> no tile imbalance; 30 prefetched loads/thread.
__global__ __launch_bounds__(256) void k_fuse(
    const float* __restrict__ sem, const float* __restrict__ roi,
    const float* __restrict__ bbx, const int* __restrict__ cls,
    int* __restrict__ out_pred, int* __restrict__ g_hist, int* __restrict__ g_scount)
{
  __shared__ InstP spar[Nn];
  __shared__ int s_all[NKEY];
  __shared__ unsigned s_rel;

  const int bid = blockIdx.x;
  const int y   = bid % Hh;
  const int b   = bid / Hh;
  const int tid = threadIdx.x;

  if (tid == 0) s_rel = 0u;
  for (int i = tid; i < NKEY; i += 256) s_all[i] = 0;
  if (tid < Nn) {
    const int n = tid;
    const float* bbp = bbx + ((size_t)b*Nn + n)*4;
    float f0 = bbp[0], f1 = bbp[1], f2 = bbp[2], f3 = bbp[3];
    int y0 = (int)floorf(f0), x0 = (int)floorf(f1);
    int y1 = (int)floorf(f2), x1 = (int)floorf(f3);
    int y1r = (int)(rintf(f2) + 1.0f);   // jnp.round = half-to-even
    int x1r = (int)(rintf(f3) + 1.0f);
    float hh = fmaxf((float)(y1 - y0 + 1), 1.0f);
    float wd = fmaxf((float)(x1 - x0 + 1), 1.0f);
    InstP p;
    p.y0 = y0; p.x0 = x0; p.y1r = y1r; p.x1r = x1r;
    p.ys = max(y0, 0); p.ye = min(y1 + 1, Hh);
    p.xs = max(x0, 0); p.xe = min(x1 + 1, Ww);
    p.sc_y = 28.0f / hh; p.sc_x = 28.0f / wd;
    int cl = cls[b*Nn + n];
    p.tc = NSs + cl;
    p.mskoff = (((b*Nn + n)*NTs) + cl)*Rr*Rr;
    spar[n] = p;
    bool rowi = (y >= y0)   && (y < y1r);
    bool rowm = (y >= p.ys) && (y < p.ye);
    if (rowi || rowm) atomicOr(&s_rel, 1u << n);
  }
  __syncthreads();

  const double EPS = (sigd(NEGD) + sigd(NEGD)) * (NEGD + NEGD);
  const float* base = sem + (size_t)b*Cch*HW + (size_t)y*Ww;

  float ch0[Cch], ch1[Cch], ch2[Cch];
#pragma unroll
  for (int c = 0; c < Cch; c++) ch0[c] = base[(size_t)c*HW + tid];
#pragma unroll
  for (int c = 0; c < Cch; c++) ch1[c] = base[(size_t)c*HW + tid + 256];
#pragma unroll
  for (int c = 0; c < Cch; c++) ch2[c] = base[(size_t)c*HW + tid + 512];

  const unsigned rel = s_rel;
  do_px(b, y, tid,       ch0, rel, spar, roi, out_pred, s_all, EPS);
  do_px(b, y, tid + 256, ch1, rel, spar, roi, out_pred, s_all, EPS);
  do_px(b, y, tid + 512, ch2, rel, spar, roi, out_pred, s_all, EPS);

  __syncthreads();
  for (int i = tid; i < NKEY; i += 256) {
    int v = s_all[i];
    if (v) {
      if (i < Nn*Cch) atomicAdd(&g_hist[b*Nn*Cch + i], v);
      else            atomicAdd(&g_scount[b*NSs + (i - Nn*Cch)], v);
    }
  }
}

// 1 block x 128 threads (2 waves, wave b = batch b). Lane n handles instance n;
// ranks via ballot+popcount -> no per-thread arrays -> no scratch (R4: VGPR 180, 66us).
__global__ __launch_bounds__(128) void k_post(
    const int* __restrict__ g_hist, const int* __restrict__ g_scount,
    const int* __restrict__ cls, int* __restrict__ lut,
    int* __restrict__ out_tail)
{
  __shared__ int sh[Bb*Nn*Cch];
  __shared__ int spc_s[Bb][NSs];
  __shared__ int pcs[Bb][40];
  const int t = threadIdx.x;
  for (int i = t; i < Bb*Nn*Cch; i += 128) sh[i] = g_hist[i];
  if (t < Bb*NSs) spc_s[t/NSs][t%NSs] = g_scount[t];
  __syncthreads();

  const int b    = t >> 6;
  const int lane = t & 63;
  const bool act = lane < Nn;

  int total = 0, mi = 0, mx = -1, tmp = 0;
  bool br2 = false, kept = false;
  if (act) {
    const int* hb = sh + b*Nn*Cch + lane*Cch;
#pragma unroll
    for (int c = 0; c < Cch; c++) { int v = hb[c]; total += v; if (v > mx) { mx = v; mi = c; } }
    tmp = cls[b*Nn + lane] + NSs;
    bool present = total > 0;
    bool b1 = (mi == tmp);
    br2  = (!b1) && (2*mx >= total) && (mi < NSs) && present;
    kept = present && !br2;
    if (br2) atomicAdd(&spc_s[b][mi], total);
  }
  __syncthreads();

  unsigned mask6 = (unsigned)(__ballot(lane < NSs && spc_s[b][lane] > 0) & 0x3Full);
  int nstuff = __popc(mask6);
  unsigned kmask = (unsigned)(__ballot(act && kept) & 0xFFFFFFFFull);
  int nk = __popc(kmask);
  int vlen = 1 + nstuff + nk;

  if (lane < NSs) lut[b*NCH + lane] = __popc(mask6 & ((1u << lane) - 1)) + 1; // absent: unused
  if (act) {
    int rk     = __popc(kmask & ((1u << lane) - 1));
    int srk_mi = __popc(mask6 & ((1u << mi) - 1));
    lut[b*NCH + NSs + lane] = kept ? (1 + nstuff + rk) : (br2 ? srk_mi + 1 : 0);
  }

  if (lane < 39) pcs[b][lane] = -1;
  __syncthreads();
  if (lane == 0) pcs[b][0] = 255;
  if (lane < NSs && ((mask6 >> lane) & 1))
    pcs[b][1 + __popc(mask6 & ((1u << lane) - 1))] = lane;
  if (act && kept)
    pcs[b][1 + nstuff + __popc(kmask & ((1u << lane) - 1))] = tmp;
  __syncthreads();

  int* pc = out_tail;                  // po_cls   [Bb][39]
  int* ic = out_tail + Bb*39;          // iscrowd  [Bb][39]
  int* vl = out_tail + 2*Bb*39;        // valid_len[Bb]
  if (lane < 39) {
    pc[b*39 + lane] = pcs[b][lane];
    ic[b*39 + lane] = (lane < vlen) ? 0 : -1;
  }
  if (lane == 0) vl[b] = vlen;
}

__global__ __launch_bounds__(256) void k_seam(int* __restrict__ pred, const int* __restrict__ lut)
{
  __shared__ int slut[Bb*NCH];
  int tid = threadIdx.x;
  if (tid < Bb*NCH) slut[tid] = lut[tid];
  __syncthreads();
  size_t i = ((size_t)blockIdx.x*256 + tid) * 4;
  int b = (int)(i / HW);   // HW divisible by 4: no straddle
  int4 v = *reinterpret_cast<int4*>(pred + i);
  int base = b*NCH;
  v.x = slut[base + v.x];
  v.y = slut[base + v.y];
  v.z = slut[base + v.z];
  v.w = slut[base + v.w];
  *reinterpret_cast<int4*>(pred + i) = v;
}

extern "C" void kernel_launch(void* const* d_in, const int* in_sizes, int n_in,
                              void* d_out, int out_size, void* d_ws, size_t ws_size,
                              hipStream_t stream)
{
  const float* sem = (const float*)d_in[0];
  const float* roi = (const float*)d_in[1];
  const float* bbx = (const float*)d_in[2];
  const int*   cls = (const int*)d_in[3];
  int* out = (int*)d_out;

  int* g_hist   = (int*)d_ws;                 // Bb*Nn*Cch = 640
  int* g_scount = g_hist + Bb*Nn*Cch;         // Bb*NSs   = 12
  int* lut      = g_scount + Bb*NSs;          // Bb*NCH   = 76

  k_zero<<<1, 256, 0, stream>>>(g_hist, Bb*Nn*Cch + Bb*NSs);
  k_fuse<<<dim3(Bb*Hh), 256, 0, stream>>>(sem, roi, bbx, cls, out, g_hist, g_scount);
  k_post<<<1, 128, 0, stream>>>(g_hist, g_scount, cls, lut, out + (size_t)Bb*HW);
  k_seam<<<dim3((Bb*HW)/(256*4)), 256, 0, stream>>>(out, lut);
}